// Round 17
// baseline (211.551 us; speedup 1.0000x reference)
//
#include <hip/hip_runtime.h>
#include <math.h>

#define N1 8192
#define N2 8192
#define KS 4096   // K-range per gemm block (2-way K-split)
// 40.5 * log2(e) and 2x that: exp(-40.5*d2) = exp2(-B2L*d2)
#define B2L  58.42914916f
#define B2L2 116.85829832f

typedef short bf16x8 __attribute__((ext_vector_type(8)));
typedef float f32x4 __attribute__((ext_vector_type(4)));
typedef unsigned short ushort8 __attribute__((ext_vector_type(8)));

// Light barrier: LDS-only coherence; in-flight global loads stay in flight.
#define LBAR() do { \
    asm volatile("s_waitcnt lgkmcnt(0)" ::: "memory"); \
    __builtin_amdgcn_s_barrier(); \
} while (0)

__device__ __forceinline__ unsigned short bf16bits(float f) {
    union { float f; unsigned u; } x; x.f = f;
    unsigned r = x.u + 0x7fff + ((x.u >> 16) & 1);   // RNE
    return (unsigned short)(r >> 16);
}

// one v_cvt_pk_bf16_f32: D[15:0]=bf16(a), D[31:16]=bf16(b)
__device__ __forceinline__ unsigned int cvt_pk_bf16(float a, float b) {
    unsigned int r;
    asm("v_cvt_pk_bf16_f32 %0, %1, %2" : "=v"(r) : "v"(a), "v"(b));
    return r;
}

// raw v_exp_f32 (2^x), no OCML guard code. Args <= 0; sub-2^-126 results
// flush toward 0, which bf16 rounds to 0 anyway.
__device__ __forceinline__ float fast_exp2(float x) {
    float r;
    asm("v_exp_f32 %0, %1" : "=v"(r) : "v"(x));
    return r;
}

// Native v_sin/v_cos: input in REVOLUTIONS, reduce with fract first.
// ~6 inst vs ~40 for OCML sincosf. Accuracy ~1e-6 rel — far below bf16/test tol.
__device__ __forceinline__ void fast_sincos(float th, float& s, float& c) {
    float r = th * 0.15915494309189535f;   // 1/(2*pi)
    r = r - floorf(r);
    asm("v_sin_f32 %0, %1" : "=v"(s) : "v"(r));
    asm("v_cos_f32 %0, %1" : "=v"(c) : "v"(r));
}

// Vf layout: [kblock = k/8][n = 0..511][e = k%8] bf16.
// n in 0..255 -> cos(p2_k . A_n); n in 256..511 -> sin(p2_k . A_n).
// Also writes q4tab[j] = {B2L2*q, -B2L*|q|^2} (per-point J-table, 128KB).
__global__ __launch_bounds__(512) void feat_kernel(const float* __restrict__ p2,
                                                   const float* __restrict__ A,
                                                   unsigned short* __restrict__ Vf,
                                                   float4* __restrict__ q4tab) {
    __shared__ float p2s[24];
    const int t = threadIdx.x;
    const int j0 = blockIdx.x * 8;
    if (t < 24) p2s[t] = p2[(size_t)j0 * 3 + t];
    __syncthreads();
    if (t < 8) {
        float x = p2s[t * 3], y = p2s[t * 3 + 1], z = p2s[t * 3 + 2];
        q4tab[j0 + t] = make_float4(B2L2 * x, B2L2 * y, B2L2 * z,
                                    -B2L * fmaf(x, x, fmaf(y, y, z * z)));
    }
    const int k = t & 255, part = t >> 8;
    const float a0 = A[k], a1 = A[256 + k], a2 = A[512 + k];
    ushort8 v8;
    #pragma unroll
    for (int j = 0; j < 8; ++j) {
        float th = fmaf(p2s[j * 3], a0, fmaf(p2s[j * 3 + 1], a1, p2s[j * 3 + 2] * a2));
        float s, c;
        fast_sincos(th, s, c);
        v8[j] = bf16bits(part ? s : c);
    }
    *(ushort8*)(Vf + (size_t)blockIdx.x * 4096 + t * 8) = v8;
}

// J tile build: 64 rows x 64 k, 512 threads -> thread owns k-pair kp (0..31)
// x rows tm + 16*rr (rr<4): 8 exp per step. J = exp2(p.q4xyz + (e1 + q4w)).
__device__ __forceinline__ void buildJ(unsigned int* __restrict__ Jdst, const int wrOfs[4],
                                       const float px[4], const float py[4],
                                       const float pz[4], const float e1[4],
                                       float4 q0, float4 q1) {
    #pragma unroll
    for (int rr = 0; rr < 4; ++rr) {
        float j0 = fast_exp2(fmaf(px[rr], q0.x, fmaf(py[rr], q0.y, fmaf(pz[rr], q0.z, e1[rr] + q0.w))));
        float j1 = fast_exp2(fmaf(px[rr], q1.x, fmaf(py[rr], q1.y, fmaf(pz[rr], q1.z, e1[rr] + q1.w))));
        *(unsigned int*)((char*)Jdst + wrOfs[rr]) = cvt_pk_bf16(j0, j1);
    }
}

__device__ __forceinline__ void loadB(bf16x8 b[2][2], const unsigned short* __restrict__ pB,
                                      const int bOfs[2][2]) {
    #pragma unroll
    for (int kk = 0; kk < 2; ++kk)
        #pragma unroll
        for (int nr = 0; nr < 2; ++nr)
            b[kk][nr] = *(const bf16x8*)(pB + bOfs[kk][nr]);
}

__device__ __forceinline__ void mfmaStep(f32x4 acc[4][2], const unsigned int* __restrict__ Jsrc,
                                         bf16x8 b[2][2], const int rdOfs[2][4]) {
    #pragma unroll
    for (int kk = 0; kk < 2; ++kk)
        #pragma unroll
        for (int mr = 0; mr < 4; ++mr) {
            bf16x8 af = *(const bf16x8*)((const char*)Jsrc + rdOfs[kk][mr]);
            acc[mr][0] = __builtin_amdgcn_mfma_f32_16x16x32_bf16(af, b[kk][0], acc[mr][0], 0, 0, 0);
            acc[mr][1] = __builtin_amdgcn_mfma_f32_16x16x32_bf16(af, b[kk][1], acc[mr][1], 0, 0, 0);
        }
}

// BM=64 x BN=256 (cg) x K-half (ks). Grid 512, 512 threads, 2 blocks/CU.
// R14 structure (the 101us best): in-step register loadB hidden under buildJ,
// Jlds ping-pong, lgkmcnt-only barriers, q4-table J math (3 fma + add + exp).
__global__ __launch_bounds__(512, 4) void gemm_kernel(const float* __restrict__ p1,
                                                      const float4* __restrict__ q4tab,
                                                      const unsigned short* __restrict__ Vf,
                                                      float* __restrict__ pout0,
                                                      float* __restrict__ pout1) {
    __shared__ unsigned int JA[2048];   // 64 rows x 64 k bf16, XOR-swizzled
    __shared__ unsigned int JB[2048];

    const int t = threadIdx.x;
    const int l = t & 63;
    const int w = t >> 6;         // 0..7: col group (32 cols of the 256)
    const int g = l >> 4;
    const int ln = l & 15;
    const int bid = (int)blockIdx.x;
    const int cg = bid & 1;
    const int ks = (bid >> 1) & 1;
    const int i0 = (bid >> 2) * 64;
    const int k0 = ks * KS;

    // J-build: thread owns k-pair kp (0..31) x rows tm + 16*rr
    const int kp = t & 31;
    const int tm = t >> 5;        // 0..15
    const int kp2 = kp * 2;
    float px[4], py[4], pz[4], e1[4];
    int wrOfs[4];
    #pragma unroll
    for (int rr = 0; rr < 4; ++rr) {
        const float* pp = p1 + (size_t)(i0 + tm + rr * 16) * 3;
        px[rr] = pp[0]; py[rr] = pp[1]; pz[rr] = pp[2];
        e1[rr] = -B2L * fmaf(px[rr], px[rr], fmaf(py[rr], py[rr], pz[rr] * pz[rr]));
        int m = tm + rr * 16;
        wrOfs[rr] = (m * 128 + kp * 4) ^ ((m & 7) << 4);
    }

    int rdOfs[2][4];
    #pragma unroll
    for (int kk = 0; kk < 2; ++kk)
        #pragma unroll
        for (int mr = 0; mr < 4; ++mr) {
            int m = mr * 16 + ln;
            rdOfs[kk][mr] = (m * 128 + kk * 64 + g * 16) ^ ((m & 7) << 4);
        }

    int bOfs[2][2];
    #pragma unroll
    for (int kk = 0; kk < 2; ++kk)
        #pragma unroll
        for (int nr = 0; nr < 2; ++nr)
            bOfs[kk][nr] = (kk * 4 + g) * 4096 + (cg * 256 + w * 32 + nr * 16 + ln) * 8;

    f32x4 acc[4][2] = {};

    float4 qA0, qA1, qB0, qB1;

    // prologue: J(k0) -> JA, q(k0+64) -> qB
    qA0 = q4tab[k0 + kp2]; qA1 = q4tab[k0 + kp2 + 1];
    buildJ(JA, wrOfs, px, py, pz, e1, qA0, qA1);
    qB0 = q4tab[k0 + 64 + kp2]; qB1 = q4tab[k0 + 64 + kp2 + 1];

    for (int jc = k0; jc < k0 + KS; jc += 128) {
        // ---- step A: consume JA (k=jc), build JB (k=jc+64), in-step B ----
        LBAR();
        bf16x8 bS[2][2];
        loadB(bS, Vf + ((unsigned)jc >> 3) * 4096u, bOfs);   // L2 latency hides under buildJ
        buildJ(JB, wrOfs, px, py, pz, e1, qB0, qB1);
        { int kn = (jc + 128) & (N2 - 1); qA0 = q4tab[kn + kp2]; qA1 = q4tab[kn + kp2 + 1]; }
        mfmaStep(acc, JA, bS, rdOfs);
        // ---- step B: consume JB (k=jc+64), build JA (k=jc+128) ----
        LBAR();
        bf16x8 bT[2][2];
        loadB(bT, Vf + ((unsigned)((jc + 64) & (N2 - 1)) >> 3) * 4096u, bOfs);
        buildJ(JA, wrOfs, px, py, pz, e1, qA0, qA1);
        { int kn = (jc + 192) & (N2 - 1); qB0 = q4tab[kn + kp2]; qB1 = q4tab[kn + kp2 + 1]; }
        mfmaStep(acc, JB, bT, rdOfs);
    }

    // ---- store raw partial C (64 rows x 256 cols of component cg) ----
    float* outb = ks ? pout1 : pout0;
    #pragma unroll
    for (int mr = 0; mr < 4; ++mr) {
        #pragma unroll
        for (int reg = 0; reg < 4; ++reg) {
            int row = i0 + mr * 16 + g * 4 + reg;
            #pragma unroll
            for (int nr = 0; nr < 2; ++nr) {
                int kc = w * 32 + nr * 16 + ln;
                outb[((size_t)row * 256 + kc) * 2 + cg] = acc[mr][nr][reg];
            }
        }
    }
}

// Epilogue: block per row. Sum the two K-half partials, reduce row norm,
// scale to 16, rotate by conj(exp(i p1.A)), add exp(i p1.P), store in place.
__global__ __launch_bounds__(256) void epi_kernel(const float* __restrict__ p1,
                                                  const float* __restrict__ A,
                                                  const float* __restrict__ P,
                                                  const float* __restrict__ part0,
                                                  float* __restrict__ out) {
    __shared__ float wsum[4];
    const int i = blockIdx.x;
    const int k = threadIdx.x;
    const size_t idx = ((size_t)i * 256 + k) * 2;
    float2 g0 = *(const float2*)(part0 + idx);
    float2 g1 = *(const float2*)(out + idx);
    const float gr = g0.x + g1.x;
    const float gi = g0.y + g1.y;

    float sq = fmaf(gr, gr, gi * gi);
    #pragma unroll
    for (int off = 1; off < 64; off <<= 1) sq += __shfl_xor(sq, off, 64);
    if ((k & 63) == 0) wsum[k >> 6] = sq;
    __syncthreads();
    const float ns = wsum[0] + wsum[1] + wsum[2] + wsum[3];
    const float scale = 16.0f * rsqrtf(ns);

    const float x = p1[(size_t)i * 3 + 0], y = p1[(size_t)i * 3 + 1], z = p1[(size_t)i * 3 + 2];
    float th1 = fmaf(x, A[k], fmaf(y, A[256 + k], z * A[512 + k]));
    float thp = fmaf(x, P[k], fmaf(y, P[256 + k], z * P[512 + k]));
    float s1, c1, sp, cp;
    fast_sincos(th1, s1, c1);
    fast_sincos(thp, sp, cp);
    float2 res;
    res.x = fmaf(gr, c1, gi * s1) * scale + cp;
    res.y = fmaf(gi, c1, -gr * s1) * scale + sp;
    *(float2*)(out + idx) = res;
}

extern "C" void kernel_launch(void* const* d_in, const int* in_sizes, int n_in,
                              void* d_out, int out_size, void* d_ws, size_t ws_size,
                              hipStream_t stream) {
    const float* p1 = (const float*)d_in[0];
    const float* p2 = (const float*)d_in[1];
    const float* A  = (const float*)d_in[2];
    const float* P  = (const float*)d_in[3];
    unsigned short* Vf = (unsigned short*)d_ws;                      // 8192x512 bf16 = 8.39 MB
    float* part0 = (float*)((char*)d_ws + (size_t)8388608);          // 8192x512 f32 = 16.8 MB
    float4* q4tab = (float4*)((char*)d_ws + (size_t)25165824);       // 8192 x 16B = 128 KB
    float* out = (float*)d_out;

    feat_kernel<<<N2 / 8, 512, 0, stream>>>(p2, A, Vf, q4tab);
    gemm_kernel<<<512, 512, 0, stream>>>(p1, q4tab, Vf, part0, out);
    epi_kernel<<<N1, 256, 0, stream>>>(p1, A, P, part0, out);
}

// Round 18
// 115.247 us; speedup vs baseline: 1.8356x; 1.8356x over previous
//
#include <hip/hip_runtime.h>
#include <math.h>

#define N1 8192
#define N2 8192
#define KS 4096   // K-range per gemm block (2-way K-split)
// 40.5 * log2(e) and 2x that: exp(-40.5*d2) = exp2(-B2L*d2)
#define B2L  58.42914916f
#define B2L2 116.85829832f

typedef short bf16x8 __attribute__((ext_vector_type(8)));
typedef float f32x4 __attribute__((ext_vector_type(4)));
typedef unsigned short ushort8 __attribute__((ext_vector_type(8)));

// Light barrier: LDS-only coherence; in-flight global loads stay in flight.
#define LBAR() do { \
    asm volatile("s_waitcnt lgkmcnt(0)" ::: "memory"); \
    __builtin_amdgcn_s_barrier(); \
} while (0)

__device__ __forceinline__ unsigned short bf16bits(float f) {
    union { float f; unsigned u; } x; x.f = f;
    unsigned r = x.u + 0x7fff + ((x.u >> 16) & 1);   // RNE
    return (unsigned short)(r >> 16);
}

// one v_cvt_pk_bf16_f32: D[15:0]=bf16(a), D[31:16]=bf16(b)
__device__ __forceinline__ unsigned int cvt_pk_bf16(float a, float b) {
    unsigned int r;
    asm("v_cvt_pk_bf16_f32 %0, %1, %2" : "=v"(r) : "v"(a), "v"(b));
    return r;
}

// raw v_exp_f32 (2^x), no OCML guard code. Args <= 0; sub-2^-126 results
// flush toward 0, which bf16 rounds to 0 anyway.
__device__ __forceinline__ float fast_exp2(float x) {
    float r;
    asm("v_exp_f32 %0, %1" : "=v"(r) : "v"(x));
    return r;
}

// Native v_sin/v_cos: input in REVOLUTIONS, reduce with fract first.
// ~6 inst vs ~40 for OCML sincosf. Validated in R17: absmax unchanged 0.0625.
__device__ __forceinline__ void fast_sincos(float th, float& s, float& c) {
    float r = th * 0.15915494309189535f;   // 1/(2*pi)
    r = r - floorf(r);
    asm("v_sin_f32 %0, %1" : "=v"(s) : "v"(r));
    asm("v_cos_f32 %0, %1" : "=v"(c) : "v"(r));
}

// Vf layout: [kblock = k/8][n = 0..511][e = k%8] bf16.
// n in 0..255 -> cos(p2_k . A_n); n in 256..511 -> sin(p2_k . A_n).
__global__ __launch_bounds__(512) void feat_kernel(const float* __restrict__ p2,
                                                   const float* __restrict__ A,
                                                   unsigned short* __restrict__ Vf) {
    __shared__ float p2s[24];
    const int t = threadIdx.x;
    const int j0 = blockIdx.x * 8;
    if (t < 24) p2s[t] = p2[(size_t)j0 * 3 + t];
    __syncthreads();
    const int k = t & 255, part = t >> 8;
    const float a0 = A[k], a1 = A[256 + k], a2 = A[512 + k];
    ushort8 v8;
    #pragma unroll
    for (int j = 0; j < 8; ++j) {
        float th = fmaf(p2s[j * 3], a0, fmaf(p2s[j * 3 + 1], a1, p2s[j * 3 + 2] * a2));
        float s, c;
        fast_sincos(th, s, c);
        v8[j] = bf16bits(part ? s : c);
    }
    *(ushort8*)(Vf + (size_t)blockIdx.x * 4096 + t * 8) = v8;
}

// qoff = kp*6 (thread-const); kbase*3 is uniform -> SALU base.
__device__ __forceinline__ void loadQ(const float* __restrict__ p2, int kbase, int qoff,
                                      float& qx0, float& qy0, float& qz0, float& e20,
                                      float& qx1, float& qy1, float& qz1, float& e21) {
    const float* q = p2 + (size_t)(unsigned)(kbase * 3) + qoff;
    qx0 = q[0]; qy0 = q[1]; qz0 = q[2];
    qx1 = q[3]; qy1 = q[4]; qz1 = q[5];
    e20 = -B2L * fmaf(qx0, qx0, fmaf(qy0, qy0, qz0 * qz0));
    e21 = -B2L * fmaf(qx1, qx1, fmaf(qy1, qy1, qz1 * qz1));
}

// J tile build: 64 rows x 64 k, 512 threads -> thread owns k-pair kp (0..31)
// x rows tm + 16*rr (rr<4): 8 exp per step.
__device__ __forceinline__ void buildJ(unsigned int* __restrict__ Jdst, const int wrOfs[4],
                                       const float px[4], const float py[4],
                                       const float pz[4], const float e1[4],
                                       float qx0, float qy0, float qz0, float e20,
                                       float qx1, float qy1, float qz1, float e21) {
    #pragma unroll
    for (int rr = 0; rr < 4; ++rr) {
        float s0 = fmaf(px[rr], qx0, fmaf(py[rr], qy0, pz[rr] * qz0));
        float s1 = fmaf(px[rr], qx1, fmaf(py[rr], qy1, pz[rr] * qz1));
        float j0 = fast_exp2(fmaf(s0, B2L2, e1[rr] + e20));
        float j1 = fast_exp2(fmaf(s1, B2L2, e1[rr] + e21));
        *(unsigned int*)((char*)Jdst + wrOfs[rr]) = cvt_pk_bf16(j0, j1);
    }
}

__device__ __forceinline__ void loadB(bf16x8 b[2][2], const unsigned short* __restrict__ pB,
                                      const int bOfs[2][2]) {
    #pragma unroll
    for (int kk = 0; kk < 2; ++kk)
        #pragma unroll
        for (int nr = 0; nr < 2; ++nr)
            b[kk][nr] = *(const bf16x8*)(pB + bOfs[kk][nr]);
}

__device__ __forceinline__ void mfmaStep(f32x4 acc[4][2], const unsigned int* __restrict__ Jsrc,
                                         bf16x8 b[2][2], const int rdOfs[2][4]) {
    #pragma unroll
    for (int kk = 0; kk < 2; ++kk)
        #pragma unroll
        for (int mr = 0; mr < 4; ++mr) {
            bf16x8 af = *(const bf16x8*)((const char*)Jsrc + rdOfs[kk][mr]);
            acc[mr][0] = __builtin_amdgcn_mfma_f32_16x16x32_bf16(af, b[kk][0], acc[mr][0], 0, 0, 0);
            acc[mr][1] = __builtin_amdgcn_mfma_f32_16x16x32_bf16(af, b[kk][1], acc[mr][1], 0, 0, 0);
        }
}

// BM=64 x BN=256 (cg) x K-half (ks). Grid 512, 512 threads, 2 blocks/CU.
// EXACT R14 gemm (101us best): in-step register loadB hidden under buildJ,
// loadQ from p2 (narrow scalar prefetch regs — the compiler keeps these
// hoisted at VGPR 64; R17's float4 q-table prefetch got sunk -> 2x slower).
__global__ __launch_bounds__(512, 4) void gemm_kernel(const float* __restrict__ p1,
                                                      const float* __restrict__ p2,
                                                      const unsigned short* __restrict__ Vf,
                                                      float* __restrict__ pout0,
                                                      float* __restrict__ pout1) {
    __shared__ unsigned int JA[2048];   // 64 rows x 64 k bf16, XOR-swizzled
    __shared__ unsigned int JB[2048];

    const int t = threadIdx.x;
    const int l = t & 63;
    const int w = t >> 6;         // 0..7: col group (32 cols of the 256)
    const int g = l >> 4;
    const int ln = l & 15;
    const int bid = (int)blockIdx.x;
    const int cg = bid & 1;
    const int ks = (bid >> 1) & 1;
    const int i0 = (bid >> 2) * 64;
    const int k0 = ks * KS;

    // J-build: thread owns k-pair kp (0..31) x rows tm + 16*rr
    const int kp = t & 31;
    const int tm = t >> 5;        // 0..15
    const int qoff = kp * 6;
    float px[4], py[4], pz[4], e1[4];
    int wrOfs[4];
    #pragma unroll
    for (int rr = 0; rr < 4; ++rr) {
        const float* pp = p1 + (size_t)(i0 + tm + rr * 16) * 3;
        px[rr] = pp[0]; py[rr] = pp[1]; pz[rr] = pp[2];
        e1[rr] = -B2L * fmaf(px[rr], px[rr], fmaf(py[rr], py[rr], pz[rr] * pz[rr]));
        int m = tm + rr * 16;
        wrOfs[rr] = (m * 128 + kp * 4) ^ ((m & 7) << 4);
    }

    int rdOfs[2][4];
    #pragma unroll
    for (int kk = 0; kk < 2; ++kk)
        #pragma unroll
        for (int mr = 0; mr < 4; ++mr) {
            int m = mr * 16 + ln;
            rdOfs[kk][mr] = (m * 128 + kk * 64 + g * 16) ^ ((m & 7) << 4);
        }

    int bOfs[2][2];
    #pragma unroll
    for (int kk = 0; kk < 2; ++kk)
        #pragma unroll
        for (int nr = 0; nr < 2; ++nr)
            bOfs[kk][nr] = (kk * 4 + g) * 4096 + (cg * 256 + w * 32 + nr * 16 + ln) * 8;

    f32x4 acc[4][2] = {};

    float qx0, qy0, qz0, e20, qx1, qy1, qz1, e21;   // q set "A-side"
    float rx0, ry0, rz0, f20, rx1, ry1, rz1, f21;   // q set "B-side"

    // prologue: J(k0) -> JA, q(k0+64) -> r
    loadQ(p2, k0, qoff, qx0, qy0, qz0, e20, qx1, qy1, qz1, e21);
    buildJ(JA, wrOfs, px, py, pz, e1, qx0, qy0, qz0, e20, qx1, qy1, qz1, e21);
    loadQ(p2, k0 + 64, qoff, rx0, ry0, rz0, f20, rx1, ry1, rz1, f21);

    for (int jc = k0; jc < k0 + KS; jc += 128) {
        // ---- step A: consume JA (k=jc), build JB (k=jc+64), in-step B ----
        LBAR();
        bf16x8 bS[2][2];
        loadB(bS, Vf + ((unsigned)jc >> 3) * 4096u, bOfs);   // L2 latency hides under buildJ
        buildJ(JB, wrOfs, px, py, pz, e1, rx0, ry0, rz0, f20, rx1, ry1, rz1, f21);
        loadQ(p2, (jc + 128) & (N2 - 1), qoff, qx0, qy0, qz0, e20, qx1, qy1, qz1, e21);
        mfmaStep(acc, JA, bS, rdOfs);
        // ---- step B: consume JB (k=jc+64), build JA (k=jc+128) ----
        LBAR();
        bf16x8 bT[2][2];
        loadB(bT, Vf + ((unsigned)((jc + 64) & (N2 - 1)) >> 3) * 4096u, bOfs);
        buildJ(JA, wrOfs, px, py, pz, e1, qx0, qy0, qz0, e20, qx1, qy1, qz1, e21);
        loadQ(p2, (jc + 192) & (N2 - 1), qoff, rx0, ry0, rz0, f20, rx1, ry1, rz1, f21);
        mfmaStep(acc, JB, bT, rdOfs);
    }

    // ---- store raw partial C (64 rows x 256 cols of component cg) ----
    float* outb = ks ? pout1 : pout0;
    #pragma unroll
    for (int mr = 0; mr < 4; ++mr) {
        #pragma unroll
        for (int reg = 0; reg < 4; ++reg) {
            int row = i0 + mr * 16 + g * 4 + reg;
            #pragma unroll
            for (int nr = 0; nr < 2; ++nr) {
                int kc = w * 32 + nr * 16 + ln;
                outb[((size_t)row * 256 + kc) * 2 + cg] = acc[mr][nr][reg];
            }
        }
    }
}

// Epilogue: block per row. Sum the two K-half partials, reduce row norm,
// scale to 16, rotate by conj(exp(i p1.A)), add exp(i p1.P), store in place.
__global__ __launch_bounds__(256) void epi_kernel(const float* __restrict__ p1,
                                                  const float* __restrict__ A,
                                                  const float* __restrict__ P,
                                                  const float* __restrict__ part0,
                                                  float* __restrict__ out) {
    __shared__ float wsum[4];
    const int i = blockIdx.x;
    const int k = threadIdx.x;
    const size_t idx = ((size_t)i * 256 + k) * 2;
    float2 g0 = *(const float2*)(part0 + idx);
    float2 g1 = *(const float2*)(out + idx);
    const float gr = g0.x + g1.x;
    const float gi = g0.y + g1.y;

    float sq = fmaf(gr, gr, gi * gi);
    #pragma unroll
    for (int off = 1; off < 64; off <<= 1) sq += __shfl_xor(sq, off, 64);
    if ((k & 63) == 0) wsum[k >> 6] = sq;
    __syncthreads();
    const float ns = wsum[0] + wsum[1] + wsum[2] + wsum[3];
    const float scale = 16.0f * rsqrtf(ns);

    const float x = p1[(size_t)i * 3 + 0], y = p1[(size_t)i * 3 + 1], z = p1[(size_t)i * 3 + 2];
    float th1 = fmaf(x, A[k], fmaf(y, A[256 + k], z * A[512 + k]));
    float thp = fmaf(x, P[k], fmaf(y, P[256 + k], z * P[512 + k]));
    float s1, c1, sp, cp;
    fast_sincos(th1, s1, c1);
    fast_sincos(thp, sp, cp);
    float2 res;
    res.x = fmaf(gr, c1, gi * s1) * scale + cp;
    res.y = fmaf(gi, c1, -gr * s1) * scale + sp;
    *(float2*)(out + idx) = res;
}

extern "C" void kernel_launch(void* const* d_in, const int* in_sizes, int n_in,
                              void* d_out, int out_size, void* d_ws, size_t ws_size,
                              hipStream_t stream) {
    const float* p1 = (const float*)d_in[0];
    const float* p2 = (const float*)d_in[1];
    const float* A  = (const float*)d_in[2];
    const float* P  = (const float*)d_in[3];
    unsigned short* Vf = (unsigned short*)d_ws;                  // 8192x512 bf16 = 8.39 MB
    float* part0 = (float*)((char*)d_ws + (size_t)8388608);      // 8192x512 f32 = 16.8 MB
    float* out = (float*)d_out;

    feat_kernel<<<N2 / 8, 512, 0, stream>>>(p2, A, Vf);
    gemm_kernel<<<512, 512, 0, stream>>>(p1, p2, Vf, part0, out);
    epi_kernel<<<N1, 256, 0, stream>>>(p1, A, P, part0, out);
}

// Round 19
// 114.875 us; speedup vs baseline: 1.8416x; 1.0032x over previous
//
#include <hip/hip_runtime.h>
#include <math.h>

#define N1 8192
#define N2 8192
#define KS 4096   // K-range per gemm block (2-way K-split)
// 40.5 * log2(e) and 2x that: exp(-40.5*d2) = exp2(-B2L*d2)
#define B2L  58.42914916f
#define B2L2 116.85829832f

typedef short bf16x8 __attribute__((ext_vector_type(8)));
typedef float f32x4 __attribute__((ext_vector_type(4)));
typedef unsigned short ushort8 __attribute__((ext_vector_type(8)));

// Light barrier: LDS-only coherence; in-flight global loads stay in flight.
#define LBAR() do { \
    asm volatile("s_waitcnt lgkmcnt(0)" ::: "memory"); \
    __builtin_amdgcn_s_barrier(); \
} while (0)

__device__ __forceinline__ unsigned short bf16bits(float f) {
    union { float f; unsigned u; } x; x.f = f;
    unsigned r = x.u + 0x7fff + ((x.u >> 16) & 1);   // RNE
    return (unsigned short)(r >> 16);
}

// one v_cvt_pk_bf16_f32: D[15:0]=bf16(a), D[31:16]=bf16(b)
__device__ __forceinline__ unsigned int cvt_pk_bf16(float a, float b) {
    unsigned int r;
    asm("v_cvt_pk_bf16_f32 %0, %1, %2" : "=v"(r) : "v"(a), "v"(b));
    return r;
}

// raw v_exp_f32 (2^x), no OCML guard code. Args <= 0; sub-2^-126 results
// flush toward 0, which bf16 rounds to 0 anyway.
__device__ __forceinline__ float fast_exp2(float x) {
    float r;
    asm("v_exp_f32 %0, %1" : "=v"(r) : "v"(x));
    return r;
}

// Native v_sin/v_cos: input in REVOLUTIONS, reduce with fract first.
// ~6 inst vs ~40 for OCML sincosf. Validated in R17/R18: absmax unchanged.
__device__ __forceinline__ void fast_sincos(float th, float& s, float& c) {
    float r = th * 0.15915494309189535f;   // 1/(2*pi)
    r = r - floorf(r);
    asm("v_sin_f32 %0, %1" : "=v"(s) : "v"(r));
    asm("v_cos_f32 %0, %1" : "=v"(c) : "v"(r));
}

// Vf layout: [kblock = k/8][n = 0..511][e = k%8] bf16.
// n in 0..255 -> cos(p2_k . A_n); n in 256..511 -> sin(p2_k . A_n).
__global__ __launch_bounds__(512) void feat_kernel(const float* __restrict__ p2,
                                                   const float* __restrict__ A,
                                                   unsigned short* __restrict__ Vf) {
    __shared__ float p2s[24];
    const int t = threadIdx.x;
    const int j0 = blockIdx.x * 8;
    if (t < 24) p2s[t] = p2[(size_t)j0 * 3 + t];
    __syncthreads();
    const int k = t & 255, part = t >> 8;
    const float a0 = A[k], a1 = A[256 + k], a2 = A[512 + k];
    ushort8 v8;
    #pragma unroll
    for (int j = 0; j < 8; ++j) {
        float th = fmaf(p2s[j * 3], a0, fmaf(p2s[j * 3 + 1], a1, p2s[j * 3 + 2] * a2));
        float s, c;
        fast_sincos(th, s, c);
        v8[j] = bf16bits(part ? s : c);
    }
    *(ushort8*)(Vf + (size_t)blockIdx.x * 4096 + t * 8) = v8;
}

// qoff = kp*6 (thread-const); kbase*3 is uniform -> SALU base.
__device__ __forceinline__ void loadQ(const float* __restrict__ p2, int kbase, int qoff,
                                      float& qx0, float& qy0, float& qz0, float& e20,
                                      float& qx1, float& qy1, float& qz1, float& e21) {
    const float* q = p2 + (size_t)(unsigned)(kbase * 3) + qoff;
    qx0 = q[0]; qy0 = q[1]; qz0 = q[2];
    qx1 = q[3]; qy1 = q[4]; qz1 = q[5];
    e20 = -B2L * fmaf(qx0, qx0, fmaf(qy0, qy0, qz0 * qz0));
    e21 = -B2L * fmaf(qx1, qx1, fmaf(qy1, qy1, qz1 * qz1));
}

// J tile build: 64 rows x 64 k, 512 threads -> thread owns k-pair kp (0..31)
// x rows tm + 16*rr (rr<4): 8 exp per step.
__device__ __forceinline__ void buildJ(unsigned int* __restrict__ Jdst, const int wrOfs[4],
                                       const float px[4], const float py[4],
                                       const float pz[4], const float e1[4],
                                       float qx0, float qy0, float qz0, float e20,
                                       float qx1, float qy1, float qz1, float e21) {
    #pragma unroll
    for (int rr = 0; rr < 4; ++rr) {
        float s0 = fmaf(px[rr], qx0, fmaf(py[rr], qy0, pz[rr] * qz0));
        float s1 = fmaf(px[rr], qx1, fmaf(py[rr], qy1, pz[rr] * qz1));
        float j0 = fast_exp2(fmaf(s0, B2L2, e1[rr] + e20));
        float j1 = fast_exp2(fmaf(s1, B2L2, e1[rr] + e21));
        *(unsigned int*)((char*)Jdst + wrOfs[rr]) = cvt_pk_bf16(j0, j1);
    }
}

__device__ __forceinline__ void loadB(bf16x8 b[2][2], const unsigned short* __restrict__ pB,
                                      const int bOfs[2][2]) {
    #pragma unroll
    for (int kk = 0; kk < 2; ++kk)
        #pragma unroll
        for (int nr = 0; nr < 2; ++nr)
            b[kk][nr] = *(const bf16x8*)(pB + bOfs[kk][nr]);
}

__device__ __forceinline__ void mfmaStep(f32x4 acc[4][2], const unsigned int* __restrict__ Jsrc,
                                         bf16x8 b[2][2], const int rdOfs[2][4]) {
    #pragma unroll
    for (int kk = 0; kk < 2; ++kk)
        #pragma unroll
        for (int mr = 0; mr < 4; ++mr) {
            bf16x8 af = *(const bf16x8*)((const char*)Jsrc + rdOfs[kk][mr]);
            acc[mr][0] = __builtin_amdgcn_mfma_f32_16x16x32_bf16(af, b[kk][0], acc[mr][0], 0, 0, 0);
            acc[mr][1] = __builtin_amdgcn_mfma_f32_16x16x32_bf16(af, b[kk][1], acc[mr][1], 0, 0, 0);
        }
}

// BM=64 x BN=256 (cg) x K-half (ks). Grid 512, 512 threads, 2 blocks/CU.
// R14 base + SINGLE-BUFFER cross-barrier B prefetch: loadB(bS, next) sits
// at step bottom, AFTER mfmaStep consumes bS (WAR dep pins it there — no
// double allocation possible, unlike R15's dual-buffer spill). The load
// stays in flight across the lgkm-only barrier; its waitcnt lands after
// next step's barrier+buildJ+loadQ (~400cyc > L2 latency) -> B-stall gone.
__global__ __launch_bounds__(512, 4) void gemm_kernel(const float* __restrict__ p1,
                                                      const float* __restrict__ p2,
                                                      const unsigned short* __restrict__ Vf,
                                                      float* __restrict__ pout0,
                                                      float* __restrict__ pout1) {
    __shared__ unsigned int JA[2048];   // 64 rows x 64 k bf16, XOR-swizzled
    __shared__ unsigned int JB[2048];

    const int t = threadIdx.x;
    const int l = t & 63;
    const int w = t >> 6;         // 0..7: col group (32 cols of the 256)
    const int g = l >> 4;
    const int ln = l & 15;
    const int bid = (int)blockIdx.x;
    const int cg = bid & 1;
    const int ks = (bid >> 1) & 1;
    const int i0 = (bid >> 2) * 64;
    const int k0 = ks * KS;

    // J-build: thread owns k-pair kp (0..31) x rows tm + 16*rr
    const int kp = t & 31;
    const int tm = t >> 5;        // 0..15
    const int qoff = kp * 6;
    float px[4], py[4], pz[4], e1[4];
    int wrOfs[4];
    #pragma unroll
    for (int rr = 0; rr < 4; ++rr) {
        const float* pp = p1 + (size_t)(i0 + tm + rr * 16) * 3;
        px[rr] = pp[0]; py[rr] = pp[1]; pz[rr] = pp[2];
        e1[rr] = -B2L * fmaf(px[rr], px[rr], fmaf(py[rr], py[rr], pz[rr] * pz[rr]));
        int m = tm + rr * 16;
        wrOfs[rr] = (m * 128 + kp * 4) ^ ((m & 7) << 4);
    }

    int rdOfs[2][4];
    #pragma unroll
    for (int kk = 0; kk < 2; ++kk)
        #pragma unroll
        for (int mr = 0; mr < 4; ++mr) {
            int m = mr * 16 + ln;
            rdOfs[kk][mr] = (m * 128 + kk * 64 + g * 16) ^ ((m & 7) << 4);
        }

    int bOfs[2][2];
    #pragma unroll
    for (int kk = 0; kk < 2; ++kk)
        #pragma unroll
        for (int nr = 0; nr < 2; ++nr)
            bOfs[kk][nr] = (kk * 4 + g) * 4096 + (cg * 256 + w * 32 + nr * 16 + ln) * 8;

    f32x4 acc[4][2] = {};

    bf16x8 bS[2][2];   // single B buffer: reloaded after each consume (WAR-pinned)
    float qx0, qy0, qz0, e20, qx1, qy1, qz1, e21;   // q set "A-side"
    float rx0, ry0, rz0, f20, rx1, ry1, rz1, f21;   // q set "B-side"

    // prologue: J(k0) -> JA, B(k0) -> bS, q(k0+64) -> r
    loadQ(p2, k0, qoff, qx0, qy0, qz0, e20, qx1, qy1, qz1, e21);
    buildJ(JA, wrOfs, px, py, pz, e1, qx0, qy0, qz0, e20, qx1, qy1, qz1, e21);
    loadB(bS, Vf + ((unsigned)k0 >> 3) * 4096u, bOfs);
    loadQ(p2, k0 + 64, qoff, rx0, ry0, rz0, f20, rx1, ry1, rz1, f21);

    for (int jc = k0; jc < k0 + KS; jc += 128) {
        // ---- step A: consume JA+bS (k=jc); build JB; reload bS <- jc+64 ----
        LBAR();
        buildJ(JB, wrOfs, px, py, pz, e1, rx0, ry0, rz0, f20, rx1, ry1, rz1, f21);
        loadQ(p2, (jc + 128) & (N2 - 1), qoff, qx0, qy0, qz0, e20, qx1, qy1, qz1, e21);
        mfmaStep(acc, JA, bS, rdOfs);
        loadB(bS, Vf + ((unsigned)((jc + 64) & (N2 - 1)) >> 3) * 4096u, bOfs);
        // ---- step B: consume JB+bS (k=jc+64); build JA; reload bS <- jc+128 ----
        LBAR();
        buildJ(JA, wrOfs, px, py, pz, e1, qx0, qy0, qz0, e20, qx1, qy1, qz1, e21);
        loadQ(p2, (jc + 192) & (N2 - 1), qoff, rx0, ry0, rz0, f20, rx1, ry1, rz1, f21);
        mfmaStep(acc, JB, bS, rdOfs);
        loadB(bS, Vf + ((unsigned)((jc + 128) & (N2 - 1)) >> 3) * 4096u, bOfs);
    }

    // ---- store raw partial C (64 rows x 256 cols of component cg) ----
    float* outb = ks ? pout1 : pout0;
    #pragma unroll
    for (int mr = 0; mr < 4; ++mr) {
        #pragma unroll
        for (int reg = 0; reg < 4; ++reg) {
            int row = i0 + mr * 16 + g * 4 + reg;
            #pragma unroll
            for (int nr = 0; nr < 2; ++nr) {
                int kc = w * 32 + nr * 16 + ln;
                outb[((size_t)row * 256 + kc) * 2 + cg] = acc[mr][nr][reg];
            }
        }
    }
}

// Epilogue: block per row. Sum the two K-half partials, reduce row norm,
// scale to 16, rotate by conj(exp(i p1.A)), add exp(i p1.P), store in place.
__global__ __launch_bounds__(256) void epi_kernel(const float* __restrict__ p1,
                                                  const float* __restrict__ A,
                                                  const float* __restrict__ P,
                                                  const float* __restrict__ part0,
                                                  float* __restrict__ out) {
    __shared__ float wsum[4];
    const int i = blockIdx.x;
    const int k = threadIdx.x;
    const size_t idx = ((size_t)i * 256 + k) * 2;
    float2 g0 = *(const float2*)(part0 + idx);
    float2 g1 = *(const float2*)(out + idx);
    const float gr = g0.x + g1.x;
    const float gi = g0.y + g1.y;

    float sq = fmaf(gr, gr, gi * gi);
    #pragma unroll
    for (int off = 1; off < 64; off <<= 1) sq += __shfl_xor(sq, off, 64);
    if ((k & 63) == 0) wsum[k >> 6] = sq;
    __syncthreads();
    const float ns = wsum[0] + wsum[1] + wsum[2] + wsum[3];
    const float scale = 16.0f * rsqrtf(ns);

    const float x = p1[(size_t)i * 3 + 0], y = p1[(size_t)i * 3 + 1], z = p1[(size_t)i * 3 + 2];
    float th1 = fmaf(x, A[k], fmaf(y, A[256 + k], z * A[512 + k]));
    float thp = fmaf(x, P[k], fmaf(y, P[256 + k], z * P[512 + k]));
    float s1, c1, sp, cp;
    fast_sincos(th1, s1, c1);
    fast_sincos(thp, sp, cp);
    float2 res;
    res.x = fmaf(gr, c1, gi * s1) * scale + cp;
    res.y = fmaf(gi, c1, -gr * s1) * scale + sp;
    *(float2*)(out + idx) = res;
}

extern "C" void kernel_launch(void* const* d_in, const int* in_sizes, int n_in,
                              void* d_out, int out_size, void* d_ws, size_t ws_size,
                              hipStream_t stream) {
    const float* p1 = (const float*)d_in[0];
    const float* p2 = (const float*)d_in[1];
    const float* A  = (const float*)d_in[2];
    const float* P  = (const float*)d_in[3];
    unsigned short* Vf = (unsigned short*)d_ws;                  // 8192x512 bf16 = 8.39 MB
    float* part0 = (float*)((char*)d_ws + (size_t)8388608);      // 8192x512 f32 = 16.8 MB
    float* out = (float*)d_out;

    feat_kernel<<<N2 / 8, 512, 0, stream>>>(p2, A, Vf);
    gemm_kernel<<<512, 512, 0, stream>>>(p1, p2, Vf, part0, out);
    epi_kernel<<<N1, 256, 0, stream>>>(p1, A, P, part0, out);
}

// Round 20
// 108.783 us; speedup vs baseline: 1.9447x; 1.0560x over previous
//
#include <hip/hip_runtime.h>
#include <math.h>

#define N1 8192
#define N2 8192
#define KS 4096   // K-range per gemm block (2-way K-split)
#define PLANE (8192 * 256)   // elements per [row][kc] partial plane
// 40.5 * log2(e) and 2x that: exp(-40.5*d2) = exp2(-B2L*d2)
#define B2L  58.42914916f
#define B2L2 116.85829832f

typedef short bf16x8 __attribute__((ext_vector_type(8)));
typedef float f32x4 __attribute__((ext_vector_type(4)));
typedef unsigned short ushort8 __attribute__((ext_vector_type(8)));

// Light barrier: LDS-only coherence; in-flight global loads stay in flight.
#define LBAR() do { \
    asm volatile("s_waitcnt lgkmcnt(0)" ::: "memory"); \
    __builtin_amdgcn_s_barrier(); \
} while (0)

__device__ __forceinline__ unsigned short bf16bits(float f) {
    union { float f; unsigned u; } x; x.f = f;
    unsigned r = x.u + 0x7fff + ((x.u >> 16) & 1);   // RNE
    return (unsigned short)(r >> 16);
}

__device__ __forceinline__ float bf2f(unsigned short b) {
    union { unsigned u; float f; } x; x.u = (unsigned)b << 16;
    return x.f;
}

// one v_cvt_pk_bf16_f32: D[15:0]=bf16(a), D[31:16]=bf16(b)
__device__ __forceinline__ unsigned int cvt_pk_bf16(float a, float b) {
    unsigned int r;
    asm("v_cvt_pk_bf16_f32 %0, %1, %2" : "=v"(r) : "v"(a), "v"(b));
    return r;
}

// raw v_exp_f32 (2^x), no OCML guard code. Args <= 0; sub-2^-126 results
// flush toward 0, which bf16 rounds to 0 anyway.
__device__ __forceinline__ float fast_exp2(float x) {
    float r;
    asm("v_exp_f32 %0, %1" : "=v"(r) : "v"(x));
    return r;
}

// Native v_sin/v_cos: input in REVOLUTIONS, reduce with fract first.
// ~6 inst vs ~40 for OCML sincosf. Validated R17/R18: absmax unchanged.
__device__ __forceinline__ void fast_sincos(float th, float& s, float& c) {
    float r = th * 0.15915494309189535f;   // 1/(2*pi)
    r = r - floorf(r);
    asm("v_sin_f32 %0, %1" : "=v"(s) : "v"(r));
    asm("v_cos_f32 %0, %1" : "=v"(c) : "v"(r));
}

// Vf layout: [kblock = k/8][n = 0..511][e = k%8] bf16.
// n in 0..255 -> cos(p2_k . A_n); n in 256..511 -> sin(p2_k . A_n).
__global__ __launch_bounds__(512) void feat_kernel(const float* __restrict__ p2,
                                                   const float* __restrict__ A,
                                                   unsigned short* __restrict__ Vf) {
    __shared__ float p2s[24];
    const int t = threadIdx.x;
    const int j0 = blockIdx.x * 8;
    if (t < 24) p2s[t] = p2[(size_t)j0 * 3 + t];
    __syncthreads();
    const int k = t & 255, part = t >> 8;
    const float a0 = A[k], a1 = A[256 + k], a2 = A[512 + k];
    ushort8 v8;
    #pragma unroll
    for (int j = 0; j < 8; ++j) {
        float th = fmaf(p2s[j * 3], a0, fmaf(p2s[j * 3 + 1], a1, p2s[j * 3 + 2] * a2));
        float s, c;
        fast_sincos(th, s, c);
        v8[j] = bf16bits(part ? s : c);
    }
    *(ushort8*)(Vf + (size_t)blockIdx.x * 4096 + t * 8) = v8;
}

// qoff = kp*6 (thread-const); kbase*3 is uniform -> SALU base.
__device__ __forceinline__ void loadQ(const float* __restrict__ p2, int kbase, int qoff,
                                      float& qx0, float& qy0, float& qz0, float& e20,
                                      float& qx1, float& qy1, float& qz1, float& e21) {
    const float* q = p2 + (size_t)(unsigned)(kbase * 3) + qoff;
    qx0 = q[0]; qy0 = q[1]; qz0 = q[2];
    qx1 = q[3]; qy1 = q[4]; qz1 = q[5];
    e20 = -B2L * fmaf(qx0, qx0, fmaf(qy0, qy0, qz0 * qz0));
    e21 = -B2L * fmaf(qx1, qx1, fmaf(qy1, qy1, qz1 * qz1));
}

// J tile build: 64 rows x 64 k, 512 threads -> thread owns k-pair kp (0..31)
// x rows tm + 16*rr (rr<4): 8 exp per step.
__device__ __forceinline__ void buildJ(unsigned int* __restrict__ Jdst, const int wrOfs[4],
                                       const float px[4], const float py[4],
                                       const float pz[4], const float e1[4],
                                       float qx0, float qy0, float qz0, float e20,
                                       float qx1, float qy1, float qz1, float e21) {
    #pragma unroll
    for (int rr = 0; rr < 4; ++rr) {
        float s0 = fmaf(px[rr], qx0, fmaf(py[rr], qy0, pz[rr] * qz0));
        float s1 = fmaf(px[rr], qx1, fmaf(py[rr], qy1, pz[rr] * qz1));
        float j0 = fast_exp2(fmaf(s0, B2L2, e1[rr] + e20));
        float j1 = fast_exp2(fmaf(s1, B2L2, e1[rr] + e21));
        *(unsigned int*)((char*)Jdst + wrOfs[rr]) = cvt_pk_bf16(j0, j1);
    }
}

__device__ __forceinline__ void loadB(bf16x8 b[2][2], const unsigned short* __restrict__ pB,
                                      const int bOfs[2][2]) {
    #pragma unroll
    for (int kk = 0; kk < 2; ++kk)
        #pragma unroll
        for (int nr = 0; nr < 2; ++nr)
            b[kk][nr] = *(const bf16x8*)(pB + bOfs[kk][nr]);
}

__device__ __forceinline__ void mfmaStep(f32x4 acc[4][2], const unsigned int* __restrict__ Jsrc,
                                         bf16x8 b[2][2], const int rdOfs[2][4]) {
    #pragma unroll
    for (int kk = 0; kk < 2; ++kk)
        #pragma unroll
        for (int mr = 0; mr < 4; ++mr) {
            bf16x8 af = *(const bf16x8*)((const char*)Jsrc + rdOfs[kk][mr]);
            acc[mr][0] = __builtin_amdgcn_mfma_f32_16x16x32_bf16(af, b[kk][0], acc[mr][0], 0, 0, 0);
            acc[mr][1] = __builtin_amdgcn_mfma_f32_16x16x32_bf16(af, b[kk][1], acc[mr][1], 0, 0, 0);
        }
}

// BM=64 x BN=256 (cg) x K-half (ks). Grid 512, 512 threads, 2 blocks/CU.
// R19 loop (101us best, single-buffer cross-barrier B prefetch). Partials are
// now stored as PLANAR BF16 [comp][row][kc] (one contiguous 64x256 slice per
// block): halves partial write traffic (33.6 -> 16.8 MB) and epi read traffic.
// bf16 rounding of partials adds ~0.01 output absmax (threshold headroom 3x).
__global__ __launch_bounds__(512, 4) void gemm_kernel(const float* __restrict__ p1,
                                                      const float* __restrict__ p2,
                                                      const unsigned short* __restrict__ Vf,
                                                      unsigned short* __restrict__ pout0,
                                                      unsigned short* __restrict__ pout1) {
    __shared__ unsigned int JA[2048];   // 64 rows x 64 k bf16, XOR-swizzled
    __shared__ unsigned int JB[2048];

    const int t = threadIdx.x;
    const int l = t & 63;
    const int w = t >> 6;         // 0..7: col group (32 cols of the 256)
    const int g = l >> 4;
    const int ln = l & 15;
    const int bid = (int)blockIdx.x;
    const int cg = bid & 1;
    const int ks = (bid >> 1) & 1;
    const int i0 = (bid >> 2) * 64;
    const int k0 = ks * KS;

    // J-build: thread owns k-pair kp (0..31) x rows tm + 16*rr
    const int kp = t & 31;
    const int tm = t >> 5;        // 0..15
    const int qoff = kp * 6;
    float px[4], py[4], pz[4], e1[4];
    int wrOfs[4];
    #pragma unroll
    for (int rr = 0; rr < 4; ++rr) {
        const float* pp = p1 + (size_t)(i0 + tm + rr * 16) * 3;
        px[rr] = pp[0]; py[rr] = pp[1]; pz[rr] = pp[2];
        e1[rr] = -B2L * fmaf(px[rr], px[rr], fmaf(py[rr], py[rr], pz[rr] * pz[rr]));
        int m = tm + rr * 16;
        wrOfs[rr] = (m * 128 + kp * 4) ^ ((m & 7) << 4);
    }

    int rdOfs[2][4];
    #pragma unroll
    for (int kk = 0; kk < 2; ++kk)
        #pragma unroll
        for (int mr = 0; mr < 4; ++mr) {
            int m = mr * 16 + ln;
            rdOfs[kk][mr] = (m * 128 + kk * 64 + g * 16) ^ ((m & 7) << 4);
        }

    int bOfs[2][2];
    #pragma unroll
    for (int kk = 0; kk < 2; ++kk)
        #pragma unroll
        for (int nr = 0; nr < 2; ++nr)
            bOfs[kk][nr] = (kk * 4 + g) * 4096 + (cg * 256 + w * 32 + nr * 16 + ln) * 8;

    f32x4 acc[4][2] = {};

    bf16x8 bS[2][2];   // single B buffer: reloaded after each consume (WAR-pinned)
    float qx0, qy0, qz0, e20, qx1, qy1, qz1, e21;   // q set "A-side"
    float rx0, ry0, rz0, f20, rx1, ry1, rz1, f21;   // q set "B-side"

    // prologue: J(k0) -> JA, B(k0) -> bS, q(k0+64) -> r
    loadQ(p2, k0, qoff, qx0, qy0, qz0, e20, qx1, qy1, qz1, e21);
    buildJ(JA, wrOfs, px, py, pz, e1, qx0, qy0, qz0, e20, qx1, qy1, qz1, e21);
    loadB(bS, Vf + ((unsigned)k0 >> 3) * 4096u, bOfs);
    loadQ(p2, k0 + 64, qoff, rx0, ry0, rz0, f20, rx1, ry1, rz1, f21);

    for (int jc = k0; jc < k0 + KS; jc += 128) {
        // ---- step A: consume JA+bS (k=jc); build JB; reload bS <- jc+64 ----
        LBAR();
        buildJ(JB, wrOfs, px, py, pz, e1, rx0, ry0, rz0, f20, rx1, ry1, rz1, f21);
        loadQ(p2, (jc + 128) & (N2 - 1), qoff, qx0, qy0, qz0, e20, qx1, qy1, qz1, e21);
        mfmaStep(acc, JA, bS, rdOfs);
        loadB(bS, Vf + ((unsigned)((jc + 64) & (N2 - 1)) >> 3) * 4096u, bOfs);
        // ---- step B: consume JB+bS (k=jc+64); build JA; reload bS <- jc+128 ----
        LBAR();
        buildJ(JA, wrOfs, px, py, pz, e1, qx0, qy0, qz0, e20, qx1, qy1, qz1, e21);
        loadQ(p2, (jc + 192) & (N2 - 1), qoff, rx0, ry0, rz0, f20, rx1, ry1, rz1, f21);
        mfmaStep(acc, JB, bS, rdOfs);
        loadB(bS, Vf + ((unsigned)((jc + 128) & (N2 - 1)) >> 3) * 4096u, bOfs);
    }

    // ---- store raw partial C as bf16, planar [comp][row][kc] ----
    unsigned short* outb = (ks ? pout1 : pout0) + (size_t)cg * PLANE;
    #pragma unroll
    for (int mr = 0; mr < 4; ++mr) {
        #pragma unroll
        for (int reg = 0; reg < 4; ++reg) {
            int row = i0 + mr * 16 + g * 4 + reg;
            #pragma unroll
            for (int nr = 0; nr < 2; ++nr) {
                int kc = w * 32 + nr * 16 + ln;
                outb[(size_t)row * 256 + kc] = bf16bits(acc[mr][nr][reg]);
            }
        }
    }
}

// Epilogue: block per row. Sum the two bf16 K-half partials, reduce row norm,
// scale to 16, rotate by conj(exp(i p1.A)), add exp(i p1.P), write f32 out.
__global__ __launch_bounds__(256) void epi_kernel(const float* __restrict__ p1,
                                                  const float* __restrict__ A,
                                                  const float* __restrict__ P,
                                                  const unsigned short* __restrict__ part0,
                                                  const unsigned short* __restrict__ part1,
                                                  float* __restrict__ out) {
    __shared__ float wsum[4];
    const int i = blockIdx.x;
    const int k = threadIdx.x;
    const size_t rofs = (size_t)i * 256 + k;
    const float gr = bf2f(part0[rofs]) + bf2f(part1[rofs]);
    const float gi = bf2f(part0[PLANE + rofs]) + bf2f(part1[PLANE + rofs]);

    float sq = fmaf(gr, gr, gi * gi);
    #pragma unroll
    for (int off = 1; off < 64; off <<= 1) sq += __shfl_xor(sq, off, 64);
    if ((k & 63) == 0) wsum[k >> 6] = sq;
    __syncthreads();
    const float ns = wsum[0] + wsum[1] + wsum[2] + wsum[3];
    const float scale = 16.0f * rsqrtf(ns);

    const float x = p1[(size_t)i * 3 + 0], y = p1[(size_t)i * 3 + 1], z = p1[(size_t)i * 3 + 2];
    float th1 = fmaf(x, A[k], fmaf(y, A[256 + k], z * A[512 + k]));
    float thp = fmaf(x, P[k], fmaf(y, P[256 + k], z * P[512 + k]));
    float s1, c1, sp, cp;
    fast_sincos(th1, s1, c1);
    fast_sincos(thp, sp, cp);
    float2 res;
    res.x = fmaf(gr, c1, gi * s1) * scale + cp;
    res.y = fmaf(gi, c1, -gr * s1) * scale + sp;
    *(float2*)(out + rofs * 2) = res;
}

extern "C" void kernel_launch(void* const* d_in, const int* in_sizes, int n_in,
                              void* d_out, int out_size, void* d_ws, size_t ws_size,
                              hipStream_t stream) {
    const float* p1 = (const float*)d_in[0];
    const float* p2 = (const float*)d_in[1];
    const float* A  = (const float*)d_in[2];
    const float* P  = (const float*)d_in[3];
    unsigned short* Vf = (unsigned short*)d_ws;                            // 8.39 MB
    unsigned short* part0 = (unsigned short*)((char*)d_ws + 8388608);      // 8.39 MB bf16 [2][8192][256]
    unsigned short* part1 = (unsigned short*)((char*)d_ws + 16777216);     // 8.39 MB bf16
    float* out = (float*)d_out;

    feat_kernel<<<N2 / 8, 512, 0, stream>>>(p2, A, Vf);
    gemm_kernel<<<512, 512, 0, stream>>>(p1, p2, Vf, part0, part1);
    epi_kernel<<<N1, 256, 0, stream>>>(p1, A, P, part0, part1, out);
}